// Round 14
// baseline (322.535 us; speedup 1.0000x reference)
//
#include <hip/hip_runtime.h>
#include <hip/hip_bf16.h>
#include <math.h>

#define NROWS 32768
#define DD    1024
#define EE    640
#define VV    320
#define BM    128
#define KT    32      // DD/32
#define CTN   40      // EE/16

typedef __attribute__((ext_vector_type(8))) short short8;
typedef __attribute__((ext_vector_type(4))) short short4v;
typedef __attribute__((ext_vector_type(4))) float float4v;

static __device__ __forceinline__ unsigned short f2bf(float f) {
    unsigned int u = __float_as_uint(f);
    return (unsigned short)((u + 0x7fffu + ((u >> 16) & 1u)) >> 16); // RNE
}
static __device__ __forceinline__ void gload_lds16(const void* g, void* l) {
    __builtin_amdgcn_global_load_lds(
        (const __attribute__((address_space(1))) unsigned int*)g,
        (__attribute__((address_space(3))) unsigned int*)l, 16, 0, 0);
}

// Pack W [K=1024][N=640] fp32 -> bf16, MFMA fragment layout:
// frag(kt, ct): lane l, elem e  <=  W[kt*32 + (l>>4)*8 + e][ct*16 + (l&15)]
__global__ void pack_w(const float* __restrict__ W, unsigned short* __restrict__ bp)
{
    const int t = threadIdx.x;
    const int tile = blockIdx.x * 4 + (t >> 6);   // 0..1279 = kt*40+ct
    const int lane = t & 63;
    const int kt = tile / CTN, ct = tile % CTN;
    const int k0 = kt * 32 + (lane >> 4) * 8;
    const int col = ct * 16 + (lane & 15);
    unsigned short v1[8];
    #pragma unroll
    for (int e = 0; e < 8; ++e)
        v1[e] = f2bf(W[(size_t)(k0 + e) * EE + col]);
    *(short8*)(bp + ((size_t)tile * 64 + lane) * 8) = *(const short8*)v1;
}

// Fused: 256 blocks x 1024 threads. Block: 128 rows x 640 cols.
// Wave w: rg=w>>3 (64-row half), cg=w&7 (80 cols = 5 frags). acc[4][5].
// 2-phase-per-kt parity-split pipeline (T3) + counted vmcnt(9) (T4) +
// setprio around MFMA (T5). B: 6-slot x 20KB LDS ring; each HALF-tile
// (20 frags, parity (j+cg)&1) staged 4 half-phases ahead; uniform 3 VMEM
// ops/thread/phase so vmcnt(9) == "my half landed, 3 newer phases in flight".
__global__ __launch_bounds__(1024, 4) void fused_vq(
    const float* __restrict__ x, const unsigned short* __restrict__ bp,
    const float* __restrict__ bias, const float* __restrict__ cb,
    const float* __restrict__ gum, float* __restrict__ out,
    float* __restrict__ probs_rep)
{
    __shared__ unsigned short Bs[6][20 * 512];    // 6 x 20 KB ring (half-tiles)
    __shared__ unsigned short As[2][BM * 32];     // 2 x 8 KB
    __shared__ float probs_blk[EE];
    __shared__ float pmax[8][BM];
    __shared__ float psum[8][BM];
    __shared__ int   pidx[8][BM];
    __shared__ int   fidx[BM][2];
    __shared__ float finv[BM][2];

    const int t    = threadIdx.x;
    const int lane = t & 63;
    const int w    = t >> 6;            // 0..15
    const int rg   = w >> 3;            // 64-row half
    const int cg   = w & 7;             // 80-col group
    const int n0   = blockIdx.x * BM;

    // ---- stage-side frag tables: fi-th frag of parity p, enumerated (c asc, j asc) ----
    int g1e = 0, g2e = 0, g1o = 0, g2o = 0;
    {
        int cnt0 = 0, cnt1 = 0;
        #pragma unroll
        for (int c = 0; c < 8; ++c)
            #pragma unroll
            for (int j = 0; j < 5; ++j) {
                const int f = c * 5 + j;
                if (((j + c) & 1) == 0) {
                    if (cnt0 == w) g1e = f;
                    if (cnt0 == 16 + (w & 3)) g2e = f;
                    ++cnt0;
                } else {
                    if (cnt1 == w) g1o = f;
                    if (cnt1 == 16 + (w & 3)) g2o = f;
                    ++cnt1;
                }
            }
    }
    // ---- read-side: parity and within-half index of this wave's j-th frag ----
    const int b0 = (cg >> 1) * 5 + (cg & 1) * 3;   // par0 base
    const int b1 = (cg >> 1) * 5 + (cg & 1) * 2;   // par1 base
    int jpar[5], jidx[5];
    #pragma unroll
    for (int j = 0; j < 5; ++j) {
        jpar[j] = (j + cg) & 1;
        jidx[j] = (jpar[j] ? b1 : b0) + (j >> 1);
    }

    float4v acc[4][5];
    #pragma unroll
    for (int rf = 0; rf < 4; ++rf)
        #pragma unroll
        for (int ct = 0; ct < 5; ++ct)
            acc[rf][ct] = (float4v)0.f;
    short8 af[4];

    // A staging: thread t stages one float4: row r0 = t>>3, k-quad kq0 = t&7
    const int r0 = t >> 3, kq0 = t & 7;
    const int abase = (r0 >> 4)*512 + ((r0 & 15) + ((kq0 >> 1) << 4))*8 + ((kq0 & 1) << 2);
    const float* xr = x + (size_t)(n0 + r0) * DD + kq0 * 4;

    auto writeA = [&](int bb, float4 v) {
        short4v s1;
        s1[0] = (short)f2bf(v.x); s1[1] = (short)f2bf(v.y);
        s1[2] = (short)f2bf(v.z); s1[3] = (short)f2bf(v.w);
        *(short4v*)&As[bb][abase] = s1;
    };
    auto ldA = [&](int ab) {
        #pragma unroll
        for (int rf = 0; rf < 4; ++rf)
            af[rf] = *(const short8*)&As[ab][(rg*4 + rf)*512 + lane*8];
    };
    // stage one half-tile: waves 0..15 -> fi w; waves 0..3 also fi 16+w (w>=4 dup)
    auto stg = [&](int slotS, int ktS, int ga, int gb, bool dup) {
        const unsigned short* src = bp + (size_t)ktS * (CTN * 512);
        unsigned short* db = &Bs[slotS][0];
        gload_lds16(src + ((size_t)ga*64 + lane)*8, db + ((size_t)(w*64 + lane))*8);
        gload_lds16(src + ((size_t)gb*64 + lane)*8, db + ((size_t)((16 + (w & 3))*64 + lane))*8);
        if (dup)
            gload_lds16(src + ((size_t)ga*64 + lane)*8, db + ((size_t)(w*64 + lane))*8);
    };
    auto mm = [&](int slotU, int parv) {
        #pragma unroll
        for (int j = 0; j < 5; ++j) {
            if (jpar[j] == parv) {
                short8 bf = *(const short8*)&Bs[slotU][(size_t)jidx[j]*512 + lane*8];
                #pragma unroll
                for (int rf = 0; rf < 4; ++rf)
                    acc[rf][j] = __builtin_amdgcn_mfma_f32_16x16x32_bf16(af[rf], bf, acc[rf][j], 0, 0, 0);
            }
        }
    };

    // ---- prologue: x(0),x(1) first (so their waits don't drain the stages),
    // then halves h=0..3 into slots 0..3, 3 ops each => 14 ops/thread ----
    float4 pXa, pXb;
    {
        float4 a00 = *(const float4*)(xr);        // op 1
        pXb = *(const float4*)(xr + 32);          // op 2  (= x(1))
        stg(0, 0, g1e, g2e, true);                // ops 3-5
        stg(1, 0, g1o, g2o, true);                // ops 6-8
        stg(2, 1, g1e, g2e, true);                // ops 9-11
        stg(3, 1, g1o, g2o, true);                // ops 12-14
        __builtin_amdgcn_sched_barrier(0);
        writeA(0, a00);                           // compiler waits a00 only
        asm volatile("s_waitcnt lgkmcnt(0)" ::: "memory");
        __builtin_amdgcn_s_barrier();
    }

    // one kt = two phases. LR <- x(kt+2) at even phase; UR (= x(kt+1)) consumed
    // by writeA at odd phase end.
    auto ktbody = [&](int kt, float4& LR, float4& UR,
                      int su, int s1, int s4, int s5) {
        // even phase: compute parity-0 frags of slot su; stage half(kt+2, par0)
        asm volatile("s_waitcnt vmcnt(9) lgkmcnt(0)" ::: "memory");
        __builtin_amdgcn_s_barrier();
        __builtin_amdgcn_sched_barrier(0);
        stg(s4, kt + 2, g1e, g2e, false);
        LR = *(const float4*)(xr + (size_t)(kt + 2) * 32);   // 3rd VMEM op
        __builtin_amdgcn_sched_barrier(0);
        ldA(kt & 1);
        __builtin_amdgcn_s_setprio(1);
        mm(su, 0);
        __builtin_amdgcn_s_setprio(0);
        __builtin_amdgcn_sched_barrier(0);
        // odd phase: parity-1 frags of slot s1; stage half(kt+2, par1), dup 3rd op
        asm volatile("s_waitcnt vmcnt(9) lgkmcnt(0)" ::: "memory");
        __builtin_amdgcn_s_barrier();
        __builtin_amdgcn_sched_barrier(0);
        stg(s5, kt + 2, g1o, g2o, true);
        __builtin_amdgcn_sched_barrier(0);
        __builtin_amdgcn_s_setprio(1);
        mm(s1, 1);
        __builtin_amdgcn_s_setprio(0);
        __builtin_amdgcn_sched_barrier(0);
        writeA((kt + 1) & 1, UR);
    };

    int su = 0;
    for (int kt = 0; kt < KT - 2; kt += 2) {
        int s1 = su + 1; if (s1 >= 6) s1 -= 6;
        int s4 = su + 4; if (s4 >= 6) s4 -= 6;
        int s5 = su + 5; if (s5 >= 6) s5 -= 6;
        ktbody(kt, pXa, pXb, su, s1, s4, s5);
        su += 2; if (su >= 6) su -= 6;
        s1 = su + 1; if (s1 >= 6) s1 -= 6;
        s4 = su + 4; if (s4 >= 6) s4 -= 6;
        s5 = su + 5; if (s5 >= 6) s5 -= 6;
        ktbody(kt + 1, pXb, pXa, su, s1, s4, s5);
        su += 2; if (su >= 6) su -= 6;
    }
    // ---- tail: kt = KT-2 (slots 0,1), kt = KT-1 (slots 2,3); no staging ----
    asm volatile("s_waitcnt vmcnt(0) lgkmcnt(0)" ::: "memory");
    __builtin_amdgcn_s_barrier();
    __builtin_amdgcn_sched_barrier(0);
    ldA((KT - 2) & 1);
    __builtin_amdgcn_s_setprio(1); mm(0, 0); __builtin_amdgcn_s_setprio(0);
    __builtin_amdgcn_sched_barrier(0);
    asm volatile("s_waitcnt lgkmcnt(0)" ::: "memory");
    __builtin_amdgcn_s_barrier();
    __builtin_amdgcn_sched_barrier(0);
    __builtin_amdgcn_s_setprio(1); mm(1, 1); __builtin_amdgcn_s_setprio(0);
    __builtin_amdgcn_sched_barrier(0);
    writeA((KT - 1) & 1, pXb);                    // x(KT-1)
    asm volatile("s_waitcnt lgkmcnt(0)" ::: "memory");
    __builtin_amdgcn_s_barrier();
    __builtin_amdgcn_sched_barrier(0);
    ldA((KT - 1) & 1);
    __builtin_amdgcn_s_setprio(1); mm(2, 0); __builtin_amdgcn_s_setprio(0);
    __builtin_amdgcn_sched_barrier(0);
    asm volatile("s_waitcnt lgkmcnt(0)" ::: "memory");
    __builtin_amdgcn_s_barrier();
    __builtin_amdgcn_sched_barrier(0);
    __builtin_amdgcn_s_setprio(1); mm(3, 1); __builtin_amdgcn_s_setprio(0);
    __builtin_amdgcn_sched_barrier(0);

    // bias (zeros in this problem; kept faithful)
    {
        float bv[5];
        #pragma unroll
        for (int ct = 0; ct < 5; ++ct) bv[ct] = bias[cg*80 + ct*16 + (lane & 15)];
        #pragma unroll
        for (int rf = 0; rf < 4; ++rf)
            #pragma unroll
            for (int ct = 0; ct < 5; ++ct) {
                acc[rf][ct][0] += bv[ct]; acc[rf][ct][1] += bv[ct];
                acc[rf][ct][2] += bv[ct]; acc[rf][ct][3] += bv[ct];
            }
    }

    // ---- Phase A: gumbel-argmax partial + clean exp-sum partial ----
    const int g = cg >> 2;                         // 4 col-waves per group
    const int goff0 = (cg & 3)*80 + (lane & 15);   // col within group
    #pragma unroll
    for (int rf = 0; rf < 4; ++rf) {
        #pragma unroll
        for (int r = 0; r < 4; ++r) {
            const int rowA = rg*64 + rf*16 + ((lane >> 4) << 2) + r;
            const float* grow = gum + ((size_t)(n0 + rowA)*2 + g)*VV + goff0;
            float m1 = -1e30f; int bi = 0; float es = 0.f;
            #pragma unroll
            for (int ct = 0; ct < 5; ++ct) {
                float zv = acc[rf][ct][r];
                float zg = zv + grow[ct*16];
                if (zg > m1) { m1 = zg; bi = goff0 + ct*16; }
                es += __expf(zv);
            }
            #pragma unroll
            for (int off = 1; off < 16; off <<= 1) {
                float om = __shfl_xor(m1, off);
                int   ob = __shfl_xor(bi, off);
                if (om > m1 || (om == m1 && ob < bi)) { m1 = om; bi = ob; }
                es += __shfl_xor(es, off);
            }
            if ((lane & 15) == 0) {
                pmax[cg][rowA] = m1; pidx[cg][rowA] = bi; psum[cg][rowA] = es;
            }
        }
    }
    for (int c = t; c < EE; c += 1024) probs_blk[c] = 0.f;
    __syncthreads();

    // ---- Phase B: combine 4 partials per (row,group) ----
    if (t < 256) {
        const int row = t & 127, gg = t >> 7;
        float m1 = -1e30f; int bi = 0x7fffffff; float s = 0.f;
        #pragma unroll
        for (int c = 0; c < 4; ++c) {
            const float om = pmax[gg*4 + c][row];
            const int   ob = pidx[gg*4 + c][row];
            if (om > m1 || (om == m1 && ob < bi)) { m1 = om; bi = ob; }
            s += psum[gg*4 + c][row];
        }
        fidx[row][gg] = bi;
        finv[row][gg] = 1.f / s;
    }
    __syncthreads();

    // ---- Phase C: probs accumulation ----
    float pacc[5];
    #pragma unroll
    for (int ct = 0; ct < 5; ++ct) pacc[ct] = 0.f;
    #pragma unroll
    for (int rf = 0; rf < 4; ++rf) {
        #pragma unroll
        for (int r = 0; r < 4; ++r) {
            const int rowA = rg*64 + rf*16 + ((lane >> 4) << 2) + r;
            const float inv = finv[rowA][g];
            #pragma unroll
            for (int ct = 0; ct < 5; ++ct)
                pacc[ct] += __expf(acc[rf][ct][r]) * inv;
        }
    }
    #pragma unroll
    for (int off = 16; off < 64; off <<= 1)
        #pragma unroll
        for (int ct = 0; ct < 5; ++ct)
            pacc[ct] += __shfl_xor(pacc[ct], off);
    if (lane < 16) {
        #pragma unroll
        for (int ct = 0; ct < 5; ++ct)
            atomicAdd(&probs_blk[cg*80 + ct*16 + lane], pacc[ct]);
    }
    __syncthreads();

    const int rep = blockIdx.x & 7;
    for (int c = t; c < EE; c += 1024)
        atomicAdd(&probs_rep[rep*EE + c], probs_blk[c]);

    // ---- fused output: codebook gather (row-uniform idx, coalesced) ----
    for (int i = t; i < BM*256; i += 1024) {
        const int row = i >> 8, f4 = i & 255;
        const int gg  = f4 >> 7;
        const int idx = fidx[row][gg];
        const float4 v = *(const float4*)&cb[((size_t)gg*VV + idx)*512 + (size_t)(f4 & 127)*4];
        *(float4*)&out[(size_t)(n0 + row)*DD + (size_t)f4*4] = v;
    }
}

// perplexity from 8-replica probs accumulator
__global__ void perp8_kernel(const float* __restrict__ probs_rep,
                             float* __restrict__ outp)
{
    __shared__ float s0[4], s1[4];
    int t = threadIdx.x;   // 256
    float p0 = 0.f, p1 = 0.f;
    for (int c = t; c < EE; c += 256) {
        float a = 0.f;
        #pragma unroll
        for (int rp = 0; rp < 8; ++rp) a += probs_rep[rp*EE + c];
        a *= (1.0f / NROWS);
        float v = a * logf(a + 1e-7f);
        if (c < VV) p0 += v; else p1 += v;
    }
    #pragma unroll
    for (int off = 1; off < 64; off <<= 1) {
        p0 += __shfl_xor(p0, off);
        p1 += __shfl_xor(p1, off);
    }
    if ((t & 63) == 0) { s0[t >> 6] = p0; s1[t >> 6] = p1; }
    __syncthreads();
    if (t == 0) {
        float a0 = s0[0] + s0[1] + s0[2] + s0[3];
        float a1 = s1[0] + s1[1] + s1[2] + s1[3];
        outp[0] = 0.5f * (expf(-a0) + expf(-a1));
    }
}

extern "C" void kernel_launch(void* const* d_in, const int* in_sizes, int n_in,
                              void* d_out, int out_size, void* d_ws, size_t ws_size,
                              hipStream_t stream)
{
    const float* x   = (const float*)d_in[0];
    const float* W   = (const float*)d_in[1];
    const float* b   = (const float*)d_in[2];
    const float* cb  = (const float*)d_in[3];
    const float* gum = (const float*)d_in[4];
    float* out = (float*)d_out;

    // ws layout: [bp 1.31MB][probs_rep 20KB]
    char* wsp = (char*)d_ws;
    unsigned short* bp = (unsigned short*)wsp;
    const size_t bp_b = (size_t)DD*EE*2;
    float* probs_rep = (float*)(wsp + bp_b);
    const size_t pr_b = 8*EE*sizeof(float);

    hipMemsetAsync(probs_rep, 0, pr_b, stream);
    pack_w<<<320, 256, 0, stream>>>(W, bp);
    fused_vq<<<NROWS / BM, 1024, 0, stream>>>(x, bp, b, cb, gum, out, probs_rep);
    perp8_kernel<<<1, 256, 0, stream>>>(probs_rep, out + (out_size - 1));
}

// Round 15
// 116.672 us; speedup vs baseline: 2.7644x; 2.7644x over previous
//
#include <hip/hip_runtime.h>
#include <hip/hip_bf16.h>
#include <math.h>

#define NROWS 32768
#define DD    1024
#define EE    640
#define VV    320
#define BM    64
#define KT    32      // DD/32
#define CTN   40      // EE/16

typedef __attribute__((ext_vector_type(4))) float float4v;
typedef long long i64t;

static __device__ __forceinline__ void gload_lds16(const void* g, void* l) {
    __builtin_amdgcn_global_load_lds(
        (const __attribute__((address_space(1))) unsigned int*)g,
        (__attribute__((address_space(3))) unsigned int*)l, 16, 0, 0);
}

// Pack W [K=1024][N=640] fp32 -> fp8 e4m3 (scaled x16), MFMA fragment layout:
// frag(kt, ct): lane l, elem e  <=  16*W[kt*32 + (l>>4)*8 + e][ct*16 + (l&15)]
__global__ void pack_w8(const float* __restrict__ W, unsigned char* __restrict__ bp)
{
    const int t = threadIdx.x;
    const int tile = blockIdx.x * 4 + (t >> 6);   // 0..1279 = kt*40+ct
    const int lane = t & 63;
    const int kt = tile / CTN, ct = tile % CTN;
    const int k0 = kt * 32 + (lane >> 4) * 8;
    const int col = ct * 16 + (lane & 15);
    float v[8];
    #pragma unroll
    for (int e = 0; e < 8; ++e)
        v[e] = 16.0f * W[(size_t)(k0 + e) * EE + col];
    int lo = 0, hi = 0;
    lo = __builtin_amdgcn_cvt_pk_fp8_f32(v[0], v[1], lo, false);
    lo = __builtin_amdgcn_cvt_pk_fp8_f32(v[2], v[3], lo, true);
    hi = __builtin_amdgcn_cvt_pk_fp8_f32(v[4], v[5], hi, false);
    hi = __builtin_amdgcn_cvt_pk_fp8_f32(v[6], v[7], hi, true);
    int2 pk; pk.x = lo; pk.y = hi;
    *(int2*)(bp + ((size_t)tile * 64 + lane) * 8) = pk;
}

// Fused: 512 blocks x 512 threads = 2 blocks/CU (LDS ~53KB). Block: 64 rows x
// all 640 cols. Wave cg (0..7): all 64 rows (rf 0..3) x cols cg*80..+79.
// acc[4][5]. fp8 A+B (B pre-scaled x16; epilogue multiplies by 1/16).
// B: 2x20KB LDS dbuf via global_load_lds; A: 2x2KB dbuf; R6-proven 1-barrier
// dbuf pipeline (stage issued BEFORE compute). Sibling block covers drains.
__global__ __launch_bounds__(512, 4) void fused_vq(
    const float* __restrict__ x, const unsigned char* __restrict__ bp,
    const float* __restrict__ bias, const float* __restrict__ cb,
    const float* __restrict__ gum, float* __restrict__ out,
    float* __restrict__ probs_rep)
{
    __shared__ unsigned char Bs[2][32 * EE];      // 2 x 20 KB
    __shared__ unsigned char As[2][BM * 32];      // 2 x 2 KB
    __shared__ float probs_blk[EE];
    __shared__ float pmax[8][BM];
    __shared__ float psum[8][BM];
    __shared__ int   pidx[8][BM];
    __shared__ int   fidx[BM][2];
    __shared__ float finv[BM][2];

    const int t    = threadIdx.x;
    const int lane = t & 63;
    const int cg   = t >> 6;            // wave id = 80-col group
    const int n0   = blockIdx.x * BM;

    float4v acc[4][5];
    #pragma unroll
    for (int rf = 0; rf < 4; ++rf)
        #pragma unroll
        for (int ct = 0; ct < 5; ++ct)
            acc[rf][ct] = (float4v)0.f;

    // A staging: thread t stages one float4 -> 4 fp8: row r0 = t>>3, quad kq0 = t&7
    const int r0 = t >> 3, kq0 = t & 7;
    const int abase = (r0 >> 4)*512 + ((r0 & 15) + ((kq0 >> 1) << 4))*8 + ((kq0 & 1) << 2);
    const float* xr = x + (size_t)(n0 + r0) * DD + kq0 * 4;

    auto writeA = [&](int bb, float4 v) {
        int pk = 0;
        pk = __builtin_amdgcn_cvt_pk_fp8_f32(v.x, v.y, pk, false);
        pk = __builtin_amdgcn_cvt_pk_fp8_f32(v.z, v.w, pk, true);
        *(int*)&As[bb][abase] = pk;
    };
    // B staging: 1280 16B-slots per kt across 512 threads
    auto stageB = [&](int bb, int kt) {
        const unsigned char* src = bp + (size_t)kt * (32 * EE);
        gload_lds16(src + (size_t)t * 16,          &Bs[bb][t * 16]);
        gload_lds16(src + (size_t)(t + 512) * 16,  &Bs[bb][(t + 512) * 16]);
        if (t < 256)
            gload_lds16(src + (size_t)(t + 1024) * 16, &Bs[bb][(t + 1024) * 16]);
    };

    // prologue
    float4 pA = *(const float4*)(xr);
    stageB(0, 0);
    __syncthreads();              // Bs[0] staged, pA arrived
    writeA(0, pA);
    __syncthreads();              // As[0] visible

    for (int kt = 0; kt < KT; ++kt) {
        const int bb = kt & 1;
        const bool more = (kt + 1 < KT);
        if (more) {
            stageB(bb ^ 1, kt + 1);                      // async, overlaps compute
            pA = *(const float4*)(xr + (kt + 1) * 32);   // issue-early
        }
        i64t af[4];
        #pragma unroll
        for (int rf = 0; rf < 4; ++rf)
            af[rf] = *(const i64t*)&As[bb][rf*512 + lane*8];
        #pragma unroll
        for (int ct = 0; ct < 5; ++ct) {
            i64t bf = *(const i64t*)&Bs[bb][((cg*5 + ct)*64 + lane)*8];
            #pragma unroll
            for (int rf = 0; rf < 4; ++rf)
                acc[rf][ct] = __builtin_amdgcn_mfma_f32_16x16x32_fp8_fp8(af[rf], bf, acc[rf][ct], 0, 0, 0);
        }
        if (more) writeA(bb ^ 1, pA);                    // write-late
        __syncthreads();          // one barrier/kt: drains stage + A-write
    }

    // un-scale (W was x16) + bias (zeros in this problem; kept faithful)
    {
        float bv[5];
        #pragma unroll
        for (int ct = 0; ct < 5; ++ct) bv[ct] = bias[cg*80 + ct*16 + (lane & 15)];
        #pragma unroll
        for (int rf = 0; rf < 4; ++rf)
            #pragma unroll
            for (int ct = 0; ct < 5; ++ct)
                #pragma unroll
                for (int r = 0; r < 4; ++r)
                    acc[rf][ct][r] = acc[rf][ct][r] * 0.0625f + bv[ct];
    }

    // ---- Phase A: gumbel-argmax partial + clean exp-sum partial ----
    const int g = cg >> 2;                         // 4 waves per group
    const int goff0 = (cg & 3)*80 + (lane & 15);   // col within group
    #pragma unroll
    for (int rf = 0; rf < 4; ++rf) {
        #pragma unroll
        for (int r = 0; r < 4; ++r) {
            const int rowA = rf*16 + ((lane >> 4) << 2) + r;
            const float* grow = gum + ((size_t)(n0 + rowA)*2 + g)*VV + goff0;
            float m1 = -1e30f; int bi = 0; float es = 0.f;
            #pragma unroll
            for (int ct = 0; ct < 5; ++ct) {
                float zv = acc[rf][ct][r];
                float zg = zv + grow[ct*16];
                if (zg > m1) { m1 = zg; bi = goff0 + ct*16; }
                es += __expf(zv);
            }
            #pragma unroll
            for (int off = 1; off < 16; off <<= 1) {
                float om = __shfl_xor(m1, off);
                int   ob = __shfl_xor(bi, off);
                if (om > m1 || (om == m1 && ob < bi)) { m1 = om; bi = ob; }
                es += __shfl_xor(es, off);
            }
            if ((lane & 15) == 0) {
                pmax[cg][rowA] = m1; pidx[cg][rowA] = bi; psum[cg][rowA] = es;
            }
        }
    }
    for (int c = t; c < EE; c += 512) probs_blk[c] = 0.f;
    __syncthreads();

    // ---- Phase B: combine 4 partials per (row,group) ----
    if (t < 128) {
        const int row = t & 63, gg = t >> 6;
        float m1 = -1e30f; int bi = 0x7fffffff; float s = 0.f;
        #pragma unroll
        for (int c = 0; c < 4; ++c) {
            const float om = pmax[gg*4 + c][row];
            const int   ob = pidx[gg*4 + c][row];
            if (om > m1 || (om == m1 && ob < bi)) { m1 = om; bi = ob; }
            s += psum[gg*4 + c][row];
        }
        fidx[row][gg] = bi;
        finv[row][gg] = 1.f / s;
    }
    __syncthreads();

    // ---- Phase C: probs accumulation ----
    float pacc[5];
    #pragma unroll
    for (int ct = 0; ct < 5; ++ct) pacc[ct] = 0.f;
    #pragma unroll
    for (int rf = 0; rf < 4; ++rf) {
        #pragma unroll
        for (int r = 0; r < 4; ++r) {
            const int rowA = rf*16 + ((lane >> 4) << 2) + r;
            const float inv = finv[rowA][g];
            #pragma unroll
            for (int ct = 0; ct < 5; ++ct)
                pacc[ct] += __expf(acc[rf][ct][r]) * inv;
        }
    }
    #pragma unroll
    for (int off = 16; off < 64; off <<= 1)
        #pragma unroll
        for (int ct = 0; ct < 5; ++ct)
            pacc[ct] += __shfl_xor(pacc[ct], off);
    if (lane < 16) {
        #pragma unroll
        for (int ct = 0; ct < 5; ++ct)
            atomicAdd(&probs_blk[cg*80 + ct*16 + lane], pacc[ct]);
    }
    __syncthreads();

    const int rep = blockIdx.x & 7;
    for (int c = t; c < EE; c += 512)
        atomicAdd(&probs_rep[rep*EE + c], probs_blk[c]);

    // ---- output: codebook gather (row-uniform idx, coalesced) ----
    for (int i = t; i < BM*256; i += 512) {
        const int row = i >> 8, f4 = i & 255;
        const int gg  = f4 >> 7;
        const int idx = fidx[row][gg];
        const float4 v = *(const float4*)&cb[((size_t)gg*VV + idx)*512 + (size_t)(f4 & 127)*4];
        *(float4*)&out[(size_t)(n0 + row)*DD + (size_t)f4*4] = v;
    }
}

// perplexity from 8-replica probs accumulator
__global__ void perp8_kernel(const float* __restrict__ probs_rep,
                             float* __restrict__ outp)
{
    __shared__ float s0[4], s1[4];
    int t = threadIdx.x;   // 256
    float p0 = 0.f, p1 = 0.f;
    for (int c = t; c < EE; c += 256) {
        float a = 0.f;
        #pragma unroll
        for (int rp = 0; rp < 8; ++rp) a += probs_rep[rp*EE + c];
        a *= (1.0f / NROWS);
        float v = a * logf(a + 1e-7f);
        if (c < VV) p0 += v; else p1 += v;
    }
    #pragma unroll
    for (int off = 1; off < 64; off <<= 1) {
        p0 += __shfl_xor(p0, off);
        p1 += __shfl_xor(p1, off);
    }
    if ((t & 63) == 0) { s0[t >> 6] = p0; s1[t >> 6] = p1; }
    __syncthreads();
    if (t == 0) {
        float a0 = s0[0] + s0[1] + s0[2] + s0[3];
        float a1 = s1[0] + s1[1] + s1[2] + s1[3];
        outp[0] = 0.5f * (expf(-a0) + expf(-a1));
    }
}

extern "C" void kernel_launch(void* const* d_in, const int* in_sizes, int n_in,
                              void* d_out, int out_size, void* d_ws, size_t ws_size,
                              hipStream_t stream)
{
    const float* x   = (const float*)d_in[0];
    const float* W   = (const float*)d_in[1];
    const float* b   = (const float*)d_in[2];
    const float* cb  = (const float*)d_in[3];
    const float* gum = (const float*)d_in[4];
    float* out = (float*)d_out;

    // ws layout: [bp8 640KB][probs_rep 20KB]
    char* wsp = (char*)d_ws;
    unsigned char* bp = (unsigned char*)wsp;
    const size_t bp_b = (size_t)DD*EE;            // fp8: 1 byte/elem
    float* probs_rep = (float*)(wsp + bp_b);
    const size_t pr_b = 8*EE*sizeof(float);

    hipMemsetAsync(probs_rep, 0, pr_b, stream);
    pack_w8<<<320, 256, 0, stream>>>(W, bp);
    fused_vq<<<NROWS / BM, 512, 0, stream>>>(x, bp, b, cb, gum, out, probs_rep);
    perp8_kernel<<<1, 256, 0, stream>>>(probs_rep, out + (out_size - 1));
}